// Round 8
// baseline (712.643 us; speedup 1.0000x reference)
//
#include <hip/hip_runtime.h>
#include <hip/hip_cooperative_groups.h>
#include <cstdint>

namespace cg = cooperative_groups;

#define NN 100000
#define CH 128
#define NT_BLK 32
#define SCAN_B 256

typedef __bf16 bf16x8 __attribute__((ext_vector_type(8)));
typedef __bf16 bf16x4 __attribute__((ext_vector_type(4)));
typedef float  f32x4  __attribute__((ext_vector_type(4)));

__device__ __forceinline__ float b2f(unsigned short u) {
    union { unsigned int i; float f; } v; v.i = ((unsigned int)u) << 16; return v.f;
}

// ================= cooperative build: zero+convert | count | scan | add | fill =================
// One dispatch replaces {memset, count+xconv, scan_wb, scan_add, fill}.
// Grid = 1024 blocks x 256 thr, __launch_bounds__(256,4) caps VGPR at 128 ->
// 4 blocks/CU x 256 CU = 1024 co-resident (cooperative-launch requirement).
__global__ __launch_bounds__(256, 4) void k_build(
    const int* __restrict__ src, const int* __restrict__ dst, int E,
    const float* __restrict__ x, unsigned short* __restrict__ xb,
    const float* __restrict__ W1l, const float* __restrict__ W1r,
    const float* __restrict__ W2l, const float* __restrict__ W2r,
    __bf16* __restrict__ wB,
    int* __restrict__ cnt, int* __restrict__ rowptr, int* __restrict__ cur,
    int* __restrict__ bsum, int* __restrict__ csr)
{
    cg::grid_group grid = cg::this_grid();
    __shared__ int tmp[SCAN_B];
    const int t = threadIdx.x;
    const int gtid = blockIdx.x * SCAN_B + t;
    const int gsz = gridDim.x * SCAN_B;

    // ---- phase 0: zero cnt ; x -> bf16 ; weights -> MFMA fragments ----
    for (int i = gtid; i < NN; i += gsz) cnt[i] = 0;
    for (int i = gtid; i < NN * CH / 8; i += gsz) {
        const float4 a = *reinterpret_cast<const float4*>(x + (size_t)i * 8);
        const float4 c = *reinterpret_cast<const float4*>(x + (size_t)i * 8 + 4);
        bf16x8 o;
        o[0] = (__bf16)a.x; o[1] = (__bf16)a.y; o[2] = (__bf16)a.z; o[3] = (__bf16)a.w;
        o[4] = (__bf16)c.x; o[5] = (__bf16)c.y; o[6] = (__bf16)c.z; o[7] = (__bf16)c.w;
        *reinterpret_cast<bf16x8*>(xb + (size_t)i * 8) = o;
    }
    if (gtid < 8192) {
        // [layer][kt:8][nt:8][lane:64][8]: elem i = B[kt*32+(lane>>4)*8+i][nt*16+(lane&15)]
        const int l    = gtid >> 12;
        const int rem  = gtid & 4095;
        const int kt   = rem >> 9;
        const int nt   = (rem >> 6) & 7;
        const int lane = rem & 63;
        const float* Wl = l ? W2l : W1l;
        const float* Wr = l ? W2r : W1r;
        const int nn = nt * 16 + (lane & 15);
        const int k0 = kt * 32 + (lane >> 4) * 8;
        bf16x8 v;
#pragma unroll
        for (int i = 0; i < 8; ++i) {
            const int k = k0 + i;
            const float f = (k < CH) ? Wl[k * CH + nn] : Wr[(k - CH) * CH + nn];
            v[i] = (__bf16)f;
        }
        *reinterpret_cast<bf16x8*>(wB + (size_t)gtid * 8) = v;
    }
    grid.sync();

    // ---- phase 1: degree count ----
    for (int e = gtid; e < E; e += gsz) atomicAdd(&cnt[dst[e]], 1);
    grid.sync();

    // ---- phase 2: per-chunk (256-node) exclusive scan -> rowptr, totals -> bsum ----
    const int nchunks = (NN + SCAN_B - 1) / SCAN_B;   // 391
    for (int c = blockIdx.x; c < nchunks; c += gridDim.x) {
        const int i = c * SCAN_B + t;
        const int v = (i < NN) ? cnt[i] : 0;
        tmp[t] = v;
        __syncthreads();
        for (int off = 1; off < SCAN_B; off <<= 1) {
            const int tv = (t >= off) ? tmp[t - off] : 0;
            __syncthreads();
            tmp[t] += tv;
            __syncthreads();
        }
        if (i < NN) rowptr[i] = tmp[t] - v;
        if (t == SCAN_B - 1) bsum[c] = tmp[SCAN_B - 1];
        __syncthreads();
    }
    grid.sync();

    // ---- phase 3: add chunk-prefix (redundant reduce over <=391 totals), init cursor ----
    for (int c = blockIdx.x; c < nchunks; c += gridDim.x) {
        int s = 0;
        for (int j = t; j < c; j += SCAN_B) s += bsum[j];   // <=2 loads/thread
        tmp[t] = s;
        __syncthreads();
        for (int off = SCAN_B / 2; off > 0; off >>= 1) {
            if (t < off) tmp[t] += tmp[t + off];
            __syncthreads();
        }
        const int base = tmp[0];
        __syncthreads();
        const int i = c * SCAN_B + t;
        if (i < NN) { const int v = rowptr[i] + base; rowptr[i] = v; cur[i] = v; }
    }
    if (gtid == 0) rowptr[NN] = E;
    grid.sync();

    // ---- phase 4: CSR fill (dst L2-warm from phase 1) ----
    for (int e = gtid; e < E; e += gsz) {
        const int slot = atomicAdd(&cur[dst[e]], 1);
        csr[slot] = src[e];
    }
}

// ================= fused SAGE layer (MFMA) — unchanged from R7 =================
// Phase 1: bf16 gather-mean, MASKED unroll-8 (8 ushort4 loads in flight/lane);
// bf16 A-tile [32][256] (agg k<128 | skip k>=128), XOR-swizzled (G4).
// Phase 2: wave w -> rows (w>>1)*16..+15, col-half (w&1): 4 nt-tiles, K=256.
// FC=true: fused [128->1] head + sigmoid via 16-lane shfl_xor + LDS combine.
template<bool FC>
__global__ __launch_bounds__(256) void k_layer(
    const unsigned short* __restrict__ feat,
    const int* __restrict__ rowptr, const int* __restrict__ csr,
    const bf16x8* __restrict__ wfrag,
    const float* __restrict__ bias,
    const float* __restrict__ Wfc, const float* __restrict__ bfc,
    void* __restrict__ outv)
{
    __shared__ unsigned short a_lds[NT_BLK * 256];   // 16 KB
    __shared__ float red[4][16];
    char* lb = (char*)a_lds;
    const int tid = threadIdx.x;
    const int node0 = blockIdx.x * NT_BLK;

    const int g = tid >> 5;
    const int q = tid & 31;

#pragma unroll
    for (int it = 0; it < NT_BLK / 8; ++it) {
        const int r = it * 8 + g;
        const int node = node0 + r;
        const int swz = (r & 7) << 4;
        float4 s = make_float4(0.f, 0.f, 0.f, 0.f);
        bf16x4 k2 = {(__bf16)0.f, (__bf16)0.f, (__bf16)0.f, (__bf16)0.f};
        if (node < NN) {
            const int r0 = rowptr[node], r1 = rowptr[node + 1];
            const int last = r1 - 1;
            for (int rr = r0; rr < r1; rr += 8) {
                ushort4 uv[8];
                float mk[8];
#pragma unroll
                for (int u = 0; u < 8; ++u) {
                    const int p = rr + u;
                    const int idx = csr[p <= last ? p : last];
                    uv[u] = *reinterpret_cast<const ushort4*>(feat + (size_t)idx * CH + q * 4);
                    mk[u] = (p < r1) ? 1.f : 0.f;
                }
#pragma unroll
                for (int u = 0; u < 8; ++u) {
                    s.x += mk[u] * b2f(uv[u].x);
                    s.y += mk[u] * b2f(uv[u].y);
                    s.z += mk[u] * b2f(uv[u].z);
                    s.w += mk[u] * b2f(uv[u].w);
                }
            }
            const float invd = 1.0f / fmaxf((float)(r1 - r0), 1.0f);
            s.x *= invd; s.y *= invd; s.z *= invd; s.w *= invd;
            const ushort4 u = *reinterpret_cast<const ushort4*>(feat + (size_t)node * CH + q * 4);
            k2 = *reinterpret_cast<const bf16x4*>(&u);   // exact bit copy
        }
        bf16x4 a;
        a[0] = (__bf16)s.x; a[1] = (__bf16)s.y; a[2] = (__bf16)s.z; a[3] = (__bf16)s.w;
        *reinterpret_cast<bf16x4*>(lb + r * 512 + ((q * 8) ^ swz)) = a;
        *reinterpret_cast<bf16x4*>(lb + r * 512 + ((256 + q * 8) ^ swz)) = k2;
    }
    __syncthreads();

    const int lane = tid & 63;
    const int w = tid >> 6;
    const int rows16 = (w >> 1) * 16;
    const int ntbase = (w & 1) * 4;
    const int row = rows16 + (lane & 15);
    const int rswz = (row & 7) << 4;
    const int abase = row * 512;
    const int asub = (lane >> 4) * 16;

    f32x4 acc[4];
#pragma unroll
    for (int nt = 0; nt < 4; ++nt) { acc[nt][0] = 0.f; acc[nt][1] = 0.f; acc[nt][2] = 0.f; acc[nt][3] = 0.f; }

#pragma unroll
    for (int kt = 0; kt < 8; ++kt) {
        const bf16x8 a = *reinterpret_cast<const bf16x8*>(lb + abase + ((kt * 64 + asub) ^ rswz));
        const bf16x8* bp = wfrag + kt * 512 + ntbase * 64 + lane;
#pragma unroll
        for (int nt = 0; nt < 4; ++nt) {
            const bf16x8 b = bp[nt * 64];
            acc[nt] = __builtin_amdgcn_mfma_f32_16x16x32_bf16(a, b, acc[nt], 0, 0, 0);
        }
    }

    const int nbase = lane & 15;
    if (!FC) {
        __bf16* out = (__bf16*)outv;
#pragma unroll
        for (int nt = 0; nt < 4; ++nt) {
            const int ch = (ntbase + nt) * 16 + nbase;
            const float bv = bias[ch];
#pragma unroll
            for (int rr = 0; rr < 4; ++rr) {
                const int node = node0 + rows16 + (lane >> 4) * 4 + rr;
                if (node < NN)
                    out[(size_t)node * CH + ch] = (__bf16)fmaxf(acc[nt][rr] + bv, 0.0f);
            }
        }
    } else {
        float* out = (float*)outv;
        float p[4] = {0.f, 0.f, 0.f, 0.f};
#pragma unroll
        for (int nt = 0; nt < 4; ++nt) {
            const int ch = (ntbase + nt) * 16 + nbase;
            const float bv = bias[ch];
            const float wf = Wfc[ch];
#pragma unroll
            for (int rr = 0; rr < 4; ++rr)
                p[rr] += fmaxf(acc[nt][rr] + bv, 0.0f) * wf;
        }
#pragma unroll
        for (int m = 1; m < 16; m <<= 1) {
#pragma unroll
            for (int rr = 0; rr < 4; ++rr) p[rr] += __shfl_xor(p[rr], m);
        }
        if (nbase == 0) {
#pragma unroll
            for (int rr = 0; rr < 4; ++rr)
                red[w][(lane >> 4) * 4 + rr] = p[rr];
        }
        __syncthreads();
        if (tid < NT_BLK) {
            const int rloc = tid;
            const float z = (rloc < 16 ? red[0][rloc] + red[1][rloc]
                                       : red[2][rloc - 16] + red[3][rloc - 16]) + bfc[0];
            const int node = node0 + rloc;
            if (node < NN) out[node] = 1.0f / (1.0f + expf(-z));
        }
    }
}

// ================= launch =================

extern "C" void kernel_launch(void* const* d_in, const int* in_sizes, int n_in,
                              void* d_out, int out_size, void* d_ws, size_t ws_size,
                              hipStream_t stream) {
    const float* x   = (const float*)d_in[0];
    const int*   ei  = (const int*)d_in[1];
    const float* W1l = (const float*)d_in[2];
    const float* W1r = (const float*)d_in[3];
    const float* b1  = (const float*)d_in[4];
    const float* W2l = (const float*)d_in[5];
    const float* W2r = (const float*)d_in[6];
    const float* b2  = (const float*)d_in[7];
    const float* Wfc = (const float*)d_in[8];
    const float* bfc = (const float*)d_in[9];

    int E = in_sizes[1] / 2;
    const int* src = ei;
    const int* dst = ei + E;

    // ws: h1 [NN*CH bf16] | xb [NN*CH bf16] | wB [65536 bf16] | cnt | cur | rowptr | bsum | csr
    unsigned short* h1 = (unsigned short*)d_ws;
    unsigned short* xb = h1 + (size_t)NN * CH;
    __bf16* wB     = (__bf16*)(xb + (size_t)NN * CH);
    int*    cnt    = (int*)(wB + 65536);
    int*    cur    = cnt + NN;
    int*    rowptr = cur + NN;
    int*    bsum   = rowptr + NN + 1;
    int*    csr    = bsum + 512;

    // cooperative build: 1024 blocks (4/CU guaranteed by __launch_bounds__(256,4))
    void* args[] = {
        (void*)&src, (void*)&dst, (void*)&E,
        (void*)&x, (void*)&xb,
        (void*)&W1l, (void*)&W1r, (void*)&W2l, (void*)&W2r, (void*)&wB,
        (void*)&cnt, (void*)&rowptr, (void*)&cur, (void*)&bsum, (void*)&csr
    };
    hipLaunchCooperativeKernel((const void*)k_build, dim3(1024), dim3(SCAN_B),
                               args, 0, stream);

    const int blocks = (NN + NT_BLK - 1) / NT_BLK;   // 3125
    k_layer<false><<<blocks, 256, 0, stream>>>(
        xb, rowptr, csr, (const bf16x8*)wB, b1, Wfc, bfc, h1);
    k_layer<true><<<blocks, 256, 0, stream>>>(
        h1, rowptr, csr, (const bf16x8*)(wB + 32768), b2, Wfc, bfc, d_out);
}

// Round 9
// 246.241 us; speedup vs baseline: 2.8941x; 2.8941x over previous
//
#include <hip/hip_runtime.h>
#include <cstdint>

#define NN 100000
#define CH 128
#define NT_BLK 32
#define SCAN_B 256

typedef __bf16 bf16x8 __attribute__((ext_vector_type(8)));
typedef __bf16 bf16x4 __attribute__((ext_vector_type(4)));
typedef float  f32x4  __attribute__((ext_vector_type(4)));

__device__ __forceinline__ float b2f(unsigned short u) {
    union { unsigned int i; float f; } v; v.i = ((unsigned int)u) << 16; return v.f;
}

// ================= init: zero cnt | x->bf16 | weights->fragments (independent) ===
__global__ __launch_bounds__(256) void k_init(
    const float* __restrict__ x, unsigned short* __restrict__ xb,
    const float* __restrict__ W1l, const float* __restrict__ W1r,
    const float* __restrict__ W2l, const float* __restrict__ W2r,
    __bf16* __restrict__ wB, int* __restrict__ cnt)
{
    const int gtid = blockIdx.x * 256 + threadIdx.x;
    const int gsz = gridDim.x * 256;
    for (int i = gtid; i < NN; i += gsz) cnt[i] = 0;
    for (int i = gtid; i < NN * CH / 8; i += gsz) {
        const float4 a = *reinterpret_cast<const float4*>(x + (size_t)i * 8);
        const float4 c = *reinterpret_cast<const float4*>(x + (size_t)i * 8 + 4);
        bf16x8 o;
        o[0] = (__bf16)a.x; o[1] = (__bf16)a.y; o[2] = (__bf16)a.z; o[3] = (__bf16)a.w;
        o[4] = (__bf16)c.x; o[5] = (__bf16)c.y; o[6] = (__bf16)c.z; o[7] = (__bf16)c.w;
        *reinterpret_cast<bf16x8*>(xb + (size_t)i * 8) = o;
    }
    if (gtid < 8192) {
        // [layer][kt:8][nt:8][lane:64][8]: elem i = B[kt*32+(lane>>4)*8+i][nt*16+(lane&15)]
        const int l    = gtid >> 12;
        const int rem  = gtid & 4095;
        const int kt   = rem >> 9;
        const int nt   = (rem >> 6) & 7;
        const int lane = rem & 63;
        const float* Wl = l ? W2l : W1l;
        const float* Wr = l ? W2r : W1r;
        const int nn = nt * 16 + (lane & 15);
        const int k0 = kt * 32 + (lane >> 4) * 8;
        bf16x8 v;
#pragma unroll
        for (int i = 0; i < 8; ++i) {
            const int k = k0 + i;
            const float f = (k < CH) ? Wl[k * CH + nn] : Wr[(k - CH) * CH + nn];
            v[i] = (__bf16)f;
        }
        *reinterpret_cast<bf16x8*>(wB + (size_t)gtid * 8) = v;
    }
}

// ================= count + per-edge slot (rank among same-dst edges) =================
__global__ void k_count(const int* __restrict__ dst, int* __restrict__ cnt,
                        int* __restrict__ slot, int E) {
    const int e = blockIdx.x * blockDim.x + threadIdx.x;
    if (e < E) slot[e] = atomicAdd(&cnt[dst[e]], 1);
}

// ================= per-chunk exclusive scan -> rowptr, totals -> bsum =================
__global__ void k_scan(const int* __restrict__ cnt, int* __restrict__ rowptr,
                       int* __restrict__ bsum, int n) {
    __shared__ int tmp[SCAN_B];
    const int t = threadIdx.x;
    const int i = blockIdx.x * SCAN_B + t;
    const int v = (i < n) ? cnt[i] : 0;
    tmp[t] = v;
    __syncthreads();
    for (int off = 1; off < SCAN_B; off <<= 1) {
        const int tv = (t >= off) ? tmp[t - off] : 0;
        __syncthreads();
        tmp[t] += tv;
        __syncthreads();
    }
    if (i < n) rowptr[i] = tmp[t] - v;
    if (t == SCAN_B - 1) bsum[blockIdx.x] = tmp[SCAN_B - 1];
}

// ================= add chunk-prefix (<=391 totals: <=2 loads/thread) =================
__global__ void k_add(int* __restrict__ rowptr, const int* __restrict__ bsum, int n, int E) {
    __shared__ int sd[SCAN_B];
    const int t = threadIdx.x;
    int s = 0;
    for (int j = t; j < (int)blockIdx.x; j += SCAN_B) s += bsum[j];
    sd[t] = s;
    __syncthreads();
    for (int off = SCAN_B / 2; off > 0; off >>= 1) {
        if (t < off) sd[t] += sd[t + off];
        __syncthreads();
    }
    const int base = sd[0];
    const int i = blockIdx.x * SCAN_B + t;
    if (i < n) rowptr[i] += base;
    if (i == 0) rowptr[n] = E;
}

// ================= CSR fill — atomic-free (uses precomputed slot) =================
__global__ void k_fill(const int* __restrict__ src, const int* __restrict__ dst,
                       const int* __restrict__ slot, const int* __restrict__ rowptr,
                       int* __restrict__ csr, int E) {
    const int e = blockIdx.x * blockDim.x + threadIdx.x;
    if (e < E) csr[rowptr[dst[e]] + slot[e]] = src[e];
}

// ================= fused SAGE layer (MFMA) — unchanged from R7 =================
// Phase 1: bf16 gather-mean, MASKED unroll-8 (8 ushort4 loads in flight/lane);
// bf16 A-tile [32][256] (agg k<128 | skip k>=128), XOR-swizzled (G4).
// Phase 2: wave w -> rows (w>>1)*16..+15, col-half (w&1): 4 nt-tiles, K=256.
// FC=true: fused [128->1] head + sigmoid via 16-lane shfl_xor + LDS combine.
template<bool FC>
__global__ __launch_bounds__(256) void k_layer(
    const unsigned short* __restrict__ feat,
    const int* __restrict__ rowptr, const int* __restrict__ csr,
    const bf16x8* __restrict__ wfrag,
    const float* __restrict__ bias,
    const float* __restrict__ Wfc, const float* __restrict__ bfc,
    void* __restrict__ outv)
{
    __shared__ unsigned short a_lds[NT_BLK * 256];   // 16 KB
    __shared__ float red[4][16];
    char* lb = (char*)a_lds;
    const int tid = threadIdx.x;
    const int node0 = blockIdx.x * NT_BLK;

    const int g = tid >> 5;
    const int q = tid & 31;

#pragma unroll
    for (int it = 0; it < NT_BLK / 8; ++it) {
        const int r = it * 8 + g;
        const int node = node0 + r;
        const int swz = (r & 7) << 4;
        float4 s = make_float4(0.f, 0.f, 0.f, 0.f);
        bf16x4 k2 = {(__bf16)0.f, (__bf16)0.f, (__bf16)0.f, (__bf16)0.f};
        if (node < NN) {
            const int r0 = rowptr[node], r1 = rowptr[node + 1];
            const int last = r1 - 1;
            for (int rr = r0; rr < r1; rr += 8) {
                ushort4 uv[8];
                float mk[8];
#pragma unroll
                for (int u = 0; u < 8; ++u) {
                    const int p = rr + u;
                    const int idx = csr[p <= last ? p : last];
                    uv[u] = *reinterpret_cast<const ushort4*>(feat + (size_t)idx * CH + q * 4);
                    mk[u] = (p < r1) ? 1.f : 0.f;
                }
#pragma unroll
                for (int u = 0; u < 8; ++u) {
                    s.x += mk[u] * b2f(uv[u].x);
                    s.y += mk[u] * b2f(uv[u].y);
                    s.z += mk[u] * b2f(uv[u].z);
                    s.w += mk[u] * b2f(uv[u].w);
                }
            }
            const float invd = 1.0f / fmaxf((float)(r1 - r0), 1.0f);
            s.x *= invd; s.y *= invd; s.z *= invd; s.w *= invd;
            const ushort4 u = *reinterpret_cast<const ushort4*>(feat + (size_t)node * CH + q * 4);
            k2 = *reinterpret_cast<const bf16x4*>(&u);   // exact bit copy
        }
        bf16x4 a;
        a[0] = (__bf16)s.x; a[1] = (__bf16)s.y; a[2] = (__bf16)s.z; a[3] = (__bf16)s.w;
        *reinterpret_cast<bf16x4*>(lb + r * 512 + ((q * 8) ^ swz)) = a;
        *reinterpret_cast<bf16x4*>(lb + r * 512 + ((256 + q * 8) ^ swz)) = k2;
    }
    __syncthreads();

    const int lane = tid & 63;
    const int w = tid >> 6;
    const int rows16 = (w >> 1) * 16;
    const int ntbase = (w & 1) * 4;
    const int row = rows16 + (lane & 15);
    const int rswz = (row & 7) << 4;
    const int abase = row * 512;
    const int asub = (lane >> 4) * 16;

    f32x4 acc[4];
#pragma unroll
    for (int nt = 0; nt < 4; ++nt) { acc[nt][0] = 0.f; acc[nt][1] = 0.f; acc[nt][2] = 0.f; acc[nt][3] = 0.f; }

#pragma unroll
    for (int kt = 0; kt < 8; ++kt) {
        const bf16x8 a = *reinterpret_cast<const bf16x8*>(lb + abase + ((kt * 64 + asub) ^ rswz));
        const bf16x8* bp = wfrag + kt * 512 + ntbase * 64 + lane;
#pragma unroll
        for (int nt = 0; nt < 4; ++nt) {
            const bf16x8 b = bp[nt * 64];
            acc[nt] = __builtin_amdgcn_mfma_f32_16x16x32_bf16(a, b, acc[nt], 0, 0, 0);
        }
    }

    const int nbase = lane & 15;
    if (!FC) {
        __bf16* out = (__bf16*)outv;
#pragma unroll
        for (int nt = 0; nt < 4; ++nt) {
            const int ch = (ntbase + nt) * 16 + nbase;
            const float bv = bias[ch];
#pragma unroll
            for (int rr = 0; rr < 4; ++rr) {
                const int node = node0 + rows16 + (lane >> 4) * 4 + rr;
                if (node < NN)
                    out[(size_t)node * CH + ch] = (__bf16)fmaxf(acc[nt][rr] + bv, 0.0f);
            }
        }
    } else {
        float* out = (float*)outv;
        float p[4] = {0.f, 0.f, 0.f, 0.f};
#pragma unroll
        for (int nt = 0; nt < 4; ++nt) {
            const int ch = (ntbase + nt) * 16 + nbase;
            const float bv = bias[ch];
            const float wf = Wfc[ch];
#pragma unroll
            for (int rr = 0; rr < 4; ++rr)
                p[rr] += fmaxf(acc[nt][rr] + bv, 0.0f) * wf;
        }
#pragma unroll
        for (int m = 1; m < 16; m <<= 1) {
#pragma unroll
            for (int rr = 0; rr < 4; ++rr) p[rr] += __shfl_xor(p[rr], m);
        }
        if (nbase == 0) {
#pragma unroll
            for (int rr = 0; rr < 4; ++rr)
                red[w][(lane >> 4) * 4 + rr] = p[rr];
        }
        __syncthreads();
        if (tid < NT_BLK) {
            const int rloc = tid;
            const float z = (rloc < 16 ? red[0][rloc] + red[1][rloc]
                                       : red[2][rloc - 16] + red[3][rloc - 16]) + bfc[0];
            const int node = node0 + rloc;
            if (node < NN) out[node] = 1.0f / (1.0f + expf(-z));
        }
    }
}

// ================= launch =================

extern "C" void kernel_launch(void* const* d_in, const int* in_sizes, int n_in,
                              void* d_out, int out_size, void* d_ws, size_t ws_size,
                              hipStream_t stream) {
    const float* x   = (const float*)d_in[0];
    const int*   ei  = (const int*)d_in[1];
    const float* W1l = (const float*)d_in[2];
    const float* W1r = (const float*)d_in[3];
    const float* b1  = (const float*)d_in[4];
    const float* W2l = (const float*)d_in[5];
    const float* W2r = (const float*)d_in[6];
    const float* b2  = (const float*)d_in[7];
    const float* Wfc = (const float*)d_in[8];
    const float* bfc = (const float*)d_in[9];

    const int E = in_sizes[1] / 2;
    const int* src = ei;
    const int* dst = ei + E;

    // ws: h1 [NN*CH bf16] | xb [NN*CH bf16] | wB [65536 bf16] | cnt | rowptr | bsum | slot | csr
    unsigned short* h1 = (unsigned short*)d_ws;
    unsigned short* xb = h1 + (size_t)NN * CH;
    __bf16* wB     = (__bf16*)(xb + (size_t)NN * CH);
    int*    cnt    = (int*)(wB + 65536);
    int*    rowptr = cnt + NN;
    int*    bsum   = rowptr + NN + 1;
    int*    slot   = bsum + 512;
    int*    csr    = slot + E;

    const int nb = (NN + SCAN_B - 1) / SCAN_B;      // 391
    const int eb = (E + 255) / 256;                 // 2500

    k_init<<<2048, 256, 0, stream>>>(x, xb, W1l, W1r, W2l, W2r, wB, cnt);
    k_count<<<eb, 256, 0, stream>>>(dst, cnt, slot, E);
    k_scan<<<nb, SCAN_B, 0, stream>>>(cnt, rowptr, bsum, NN);
    k_add<<<nb, SCAN_B, 0, stream>>>(rowptr, bsum, NN, E);
    k_fill<<<eb, 256, 0, stream>>>(src, dst, slot, rowptr, csr, E);

    const int blocks = (NN + NT_BLK - 1) / NT_BLK;   // 3125
    k_layer<false><<<blocks, 256, 0, stream>>>(
        xb, rowptr, csr, (const bf16x8*)wB, b1, Wfc, bfc, h1);
    k_layer<true><<<blocks, 256, 0, stream>>>(
        h1, rowptr, csr, (const bf16x8*)(wB + 32768), b2, Wfc, bfc, d_out);
}